// Round 8
// baseline (113.748 us; speedup 1.0000x reference)
//
#include <hip/hip_runtime.h>
#include <cstdint>

#define B_    64
#define EMB   1024
#define NO    2048
#define NL    8192
#define LOUT  8190
#define NJ    128
#define NKC   16          // K-chunks in k1
#define KCH   64          // K depth per chunk
#define ALPHA 0.3989422804014327f   // 1/sqrt(2*pi): gelu(x) ~= 0.5x + ALPHA*x^2

// ---------------------------------------------------------------------------
// K1: split-K GEMM. c_part[kc][b][o] = sum_{e in chunk} token[b,e]*wdec[e,o].
// grid = 32 o-tiles(64) x 16 K-chunks(64) = 512 blocks (2/CU).
// kc==0 blocks zero F (4096 f32) and cnt (64 u32) for this iteration
// (workspace is re-poisoned before every replay). Verified round 6.
// ---------------------------------------------------------------------------
__global__ __launch_bounds__(256) void k1_gemm(const float* __restrict__ token,
                                               const float* __restrict__ wdec,
                                               float* __restrict__ c_part,
                                               float* __restrict__ F,
                                               unsigned int* __restrict__ cnt) {
    const int ot  = blockIdx.x & 31;
    const int kc  = blockIdx.x >> 5;
    const int o0  = ot * 64;
    const int kb  = kc * KCH;
    const int tid = threadIdx.x;
    const int og  = tid & 15;
    const int bg  = tid >> 4;

    if (kc == 0) {                       // re-init accumulators each iteration
        if (tid < 128) F[ot * 128 + tid] = 0.f;
        if (tid < 2)   cnt[ot * 2 + tid] = 0u;
    }

    __shared__ float tokT[KCH][68];   // [k][b], padded
    __shared__ float wdS[KCH][68];    // [k][o], padded

    {
        const int k4 = tid & 15;      // k-group of 4
        const int b0 = tid >> 4;
#pragma unroll
        for (int i = 0; i < 4; ++i) { // token tile 64b x 64k, coalesced along k
            int b = b0 + i * 16;
            float4 v = *(const float4*)&token[b * EMB + kb + k4 * 4];
            tokT[k4 * 4 + 0][b] = v.x;
            tokT[k4 * 4 + 1][b] = v.y;
            tokT[k4 * 4 + 2][b] = v.z;
            tokT[k4 * 4 + 3][b] = v.w;
        }
        const int o4 = tid & 15;
        const int k0 = tid >> 4;
#pragma unroll
        for (int i = 0; i < 4; ++i) { // wdec tile 64k x 64o, coalesced along o
            int k = k0 + i * 16;
            *(float4*)&wdS[k][o4 * 4] = *(const float4*)&wdec[(kb + k) * NO + o0 + o4 * 4];
        }
    }
    __syncthreads();

    float acc[4][4] = {};
#pragma unroll 4
    for (int k = 0; k < KCH; ++k) {
        float4 tv = *(const float4*)&tokT[k][bg * 4];
        float4 wv = *(const float4*)&wdS[k][og * 4];
        acc[0][0] = fmaf(tv.x, wv.x, acc[0][0]);
        acc[0][1] = fmaf(tv.x, wv.y, acc[0][1]);
        acc[0][2] = fmaf(tv.x, wv.z, acc[0][2]);
        acc[0][3] = fmaf(tv.x, wv.w, acc[0][3]);
        acc[1][0] = fmaf(tv.y, wv.x, acc[1][0]);
        acc[1][1] = fmaf(tv.y, wv.y, acc[1][1]);
        acc[1][2] = fmaf(tv.y, wv.z, acc[1][2]);
        acc[1][3] = fmaf(tv.y, wv.w, acc[1][3]);
        acc[2][0] = fmaf(tv.z, wv.x, acc[2][0]);
        acc[2][1] = fmaf(tv.z, wv.y, acc[2][1]);
        acc[2][2] = fmaf(tv.z, wv.z, acc[2][2]);
        acc[2][3] = fmaf(tv.z, wv.w, acc[2][3]);
        acc[3][0] = fmaf(tv.w, wv.x, acc[3][0]);
        acc[3][1] = fmaf(tv.w, wv.y, acc[3][1]);
        acc[3][2] = fmaf(tv.w, wv.z, acc[3][2]);
        acc[3][3] = fmaf(tv.w, wv.w, acc[3][3]);
    }

    float* cp = c_part + kc * (B_ * NO) + o0 + og * 4;
#pragma unroll
    for (int ib = 0; ib < 4; ++ib) {
        float4 v = {acc[ib][0], acc[ib][1], acc[ib][2], acc[ib][3]};
        *(float4*)&cp[(bg * 4 + ib) * NO] = v;
    }
}

// ---------------------------------------------------------------------------
// K2: fold + DISTRIBUTED eval tail. 256 blocks x 256 thr, one block per
// (b, j-quarter); XCD-grouped remap keeps the 4 sibling blocks of a b on one
// XCD (shared L2 for c_part reuse AND for the F/cnt atomics below).
// Each block atomically merges its quarter spectrum into F[b][64], then ALL
// 4 siblings spin until the merge completes (co-resident: grid=256 <= 256
// CUs) and EACH evaluates its own quarter of the 8190 output points via the
// HW-verified 4-fold-symmetry recurrence — same per-block work as the old
// standalone k3, no concentration (round-6 lesson), no k3 dispatch gap.
// ---------------------------------------------------------------------------
__global__ __launch_bounds__(256) void k2_fused(const float* __restrict__ c_part,
                                                const float* __restrict__ bdec,
                                                const float* __restrict__ w1,
                                                const float* __restrict__ b1,
                                                const float* __restrict__ w2,
                                                const float* __restrict__ b2,
                                                float* __restrict__ F,
                                                unsigned int* __restrict__ cnt,
                                                float* __restrict__ out) {
    const int bid = blockIdx.x;
    const int xg  = bid & 7;                 // XCD slot
    const int q4  = (bid >> 3) & 3;          // j-quarter
    const int b   = (bid >> 5) * 8 + xg;     // batch
    const int j0  = q4 * 32;
    const int t   = threadIdx.x;

    __shared__ float cwS[2048];          // summed c + bdec, [w*32+m]
    __shared__ float w1S[2048];          // w1 slice, [w*32+jl]
    __shared__ float w2S[32], b1S[32];
    __shared__ float aspec[32 * 32];     // [jl*32 + m]: C_k at 2k, S_k at 2k+1
    __shared__ float FpS[4][64];
    __shared__ float Fsh[64];

    // ---- stage: sum the 16 split-K partials + bdec (inline reduce) ----
    {
        const float4* cp4 = (const float4*)c_part;
        const float4* bd4 = (const float4*)bdec;
#pragma unroll
        for (int i = 0; i < 2; ++i) {
            int s = t + i * 256;                 // float4 slot 0..511
            float4 v = bd4[s];
#pragma unroll
            for (int kc = 0; kc < NKC; ++kc) {
                float4 c = cp4[kc * 32768 + b * 512 + s];
                v.x += c.x; v.y += c.y; v.z += c.z; v.w += c.w;
            }
            ((float4*)cwS)[s] = v;
        }
#pragma unroll
        for (int i = 0; i < 8; ++i) {
            int e = t + i * 256;
            int w = e >> 5, jl = e & 31;
            w1S[e] = w1[w * 128 + j0 + jl];
        }
        if (t < 32) { w2S[t] = w2[j0 + t]; b1S[t] = b1[j0 + t]; }
    }
    __syncthreads();

    // ---- a-spectrum: thread (jl = t>>3, m4 = t&7) owns 4 consecutive m ----
    {
        const int m4 = t & 7, jl = t >> 3;
        float4 acc = {0.f, 0.f, 0.f, 0.f};
        const float4* cw4 = (const float4*)cwS;
        for (int w = 0; w < 64; ++w) {
            float4 cv = cw4[w * 8 + m4];
            float  wv = w1S[w * 32 + jl];
            acc.x = fmaf(cv.x, wv, acc.x);
            acc.y = fmaf(cv.y, wv, acc.y);
            acc.z = fmaf(cv.z, wv, acc.z);
            acc.w = fmaf(cv.w, wv, acc.w);
        }
        const float s2 = 2.0f / NL;
        if (m4 == 0) {
            acc.x = acc.x * (1.0f / NL) + b1S[jl];  // C_0 = A0 (incl b1)
            acc.y = 0.f;                            // S_0 = 0 (DC imag ignored)
            acc.z *= s2; acc.w *= -s2;
        } else {
            acc.x *= s2; acc.y *= -s2; acc.z *= s2; acc.w *= -s2;
        }
        ((float4*)aspec)[jl * 8 + m4] = acc;
    }
    __syncthreads();

    // ---- gather-fold: thread (m = t&31, jq = t>>5) covers 4 j's ----
    {
        const int m  = t & 31;
        const int jq = t >> 5;
        float rc = 0.f, rs = 0.f;
        for (int r = 0; r < 4; ++r) {
            const int jl = r * 8 + jq;
            const float* A = aspec + jl * 32;
            const float C0 = A[0];
            float Qc, Qs, lc, ls;
            if (m == 0) {
                float ssum = 0.f;
#pragma unroll
                for (int k = 1; k <= 15; ++k)
                    ssum += A[2 * k] * A[2 * k] + A[2 * k + 1] * A[2 * k + 1];
                Qc = fmaf(C0, C0, 0.5f * ssum);
                Qs = 0.f; lc = C0; ls = 0.f;
            } else {
                lc = (m <= 15) ? A[2 * m]     : 0.f;
                ls = (m <= 15) ? A[2 * m + 1] : 0.f;
                Qc = 2.f * C0 * lc;
                Qs = 2.f * C0 * ls;
                int lo = m - 15; if (lo < 1)  lo = 1;
                int hi = m - 1;  if (hi > 15) hi = 15;
                for (int k1 = lo; k1 <= hi; ++k1) {        // sum-combinations
                    int k2 = m - k1;
                    float c1 = A[2 * k1], s1 = A[2 * k1 + 1];
                    float c2 = A[2 * k2], sv = A[2 * k2 + 1];
                    Qc = fmaf(0.5f, fmaf(c1, c2, -s1 * sv), Qc);
                    Qs = fmaf(0.5f, fmaf(c1, sv,  s1 * c2), Qs);
                }
                for (int k = 1; k <= 15 - m; ++k) {        // diff-combinations
                    float ch = A[2 * (k + m)], sh = A[2 * (k + m) + 1];
                    float cl = A[2 * k],       sl = A[2 * k + 1];
                    Qc = fmaf(ch, cl, Qc); Qc = fmaf(sh, sl, Qc);
                    Qs = fmaf(sh, cl, Qs); Qs = fmaf(-ch, sl, Qs);
                }
            }
            const float wj = w2S[jl];
            rc += wj * fmaf(ALPHA, Qc, 0.5f * lc);
            rs += wj * fmaf(ALPHA, Qs, 0.5f * ls);
        }
        rc += __shfl_xor(rc, 32);
        rs += __shfl_xor(rs, 32);
        if ((t & 32) == 0) {
            FpS[t >> 6][m]      = rc;
            FpS[t >> 6][32 + m] = rs;
        }
    }
    __syncthreads();
    if (t < 32) {
        float Fc = FpS[0][t] + FpS[1][t] + FpS[2][t] + FpS[3][t];
        float Fs = FpS[0][32 + t] + FpS[1][32 + t] + FpS[2][32 + t] + FpS[3][32 + t];
        if (t == 0 && q4 == 0) Fc += b2[0];
        atomicAdd(&F[b * 64 + t],      Fc);
        atomicAdd(&F[b * 64 + 32 + t], Fs);
    }
    __syncthreads();                      // all F atomics of this block issued

    // ---- sibling barrier: wait until all 4 quarter-blocks of b merged ----
    if (t == 0) {
        __threadfence();                  // release
        atomicAdd(&cnt[b], 1u);
        while (atomicAdd(&cnt[b], 0u) < 4u)   // coherent poll; siblings are
            __builtin_amdgcn_s_sleep(8);      // co-resident (grid=256<=CUs)
    }
    __syncthreads();
    __threadfence();                      // acquire
    if (t < 64) Fsh[t] = atomicAdd(&F[b * 64 + t], 0.0f);  // coherent read
    __syncthreads();

    // ---- eval tail: THIS block covers base points [q4*512, q4*512+512) ----
    // 4-fold symmetry (HW-verified): w0*2048 = pi/2.
    //   out(pt+2048q) = Fc0 + A0 + [q=0: A1+A2+A3 | q=1: B1-A2-B3 |
    //                               q=2: -A1+A2-A3 | q=3: -B1-A2+B3]
    const float w0 = 6.283185307179586f / (float)NL;
    float* ob = out + b * LOUT;
#pragma unroll
    for (int i = 0; i < 2; ++i) {
        int pt = q4 * 512 + i * 256 + t;               // [0, 2048)
        float s1, c1;
        __sincosf(w0 * (float)pt, &s1, &c1);
        float A0 = 0.f, A1 = 0.f, A2 = 0.f, A3 = 0.f, B1 = 0.f, B3 = 0.f;
        float ckm = 1.f, ck = c1, skm = 0.f, sk = s1;
        const float tc = 2.f * c1;
#pragma unroll
        for (int k = 1; k <= 30; ++k) {
            const float fc = Fsh[k], fs = Fsh[32 + k];
            if ((k & 3) == 0) {
                A0 = fmaf(fc, ck, A0); A0 = fmaf(fs, sk, A0);
            } else if ((k & 3) == 1) {
                A1 = fmaf(fc, ck, A1); A1 = fmaf(fs, sk, A1);
                B1 = fmaf(fs, ck, B1); B1 = fmaf(-fc, sk, B1);
            } else if ((k & 3) == 2) {
                A2 = fmaf(fc, ck, A2); A2 = fmaf(fs, sk, A2);
            } else {
                A3 = fmaf(fc, ck, A3); A3 = fmaf(fs, sk, A3);
                B3 = fmaf(fs, ck, B3); B3 = fmaf(-fc, sk, B3);
            }
            float cn = fmaf(tc, ck, -ckm);
            float sn = fmaf(tc, sk, -skm);
            ckm = ck; ck = cn;
            skm = sk; sk = sn;
        }
        const float S = Fsh[0] + A0;
        ob[pt]        = S + A1 + A2 + A3;
        ob[pt + 2048] = S + B1 - A2 - B3;
        ob[pt + 4096] = S - A1 + A2 - A3;
        if (pt < LOUT - 6144)
            ob[pt + 6144] = S - B1 - A2 + B3;
    }
}

extern "C" void kernel_launch(void* const* d_in, const int* in_sizes, int n_in,
                              void* d_out, int out_size, void* d_ws, size_t ws_size,
                              hipStream_t stream) {
    const float* token = (const float*)d_in[0];
    // d_in[1] = x_len (8192, hard-coded)
    const float* wdec  = (const float*)d_in[2];
    const float* bdec  = (const float*)d_in[3];
    const float* w1    = (const float*)d_in[4];
    const float* b1    = (const float*)d_in[5];
    const float* w2    = (const float*)d_in[6];
    const float* b2    = (const float*)d_in[7];
    float* out = (float*)d_out;

    float* c_part     = (float*)d_ws;                  // 16*64*2048 f32 = 8 MB
    float* F          = c_part + NKC * B_ * NO;        // 64*64 f32 = 16 KB
    unsigned int* cnt = (unsigned int*)(F + B_ * 64);  // 64 u32

    k1_gemm<<<512, 256, 0, stream>>>(token, wdec, c_part, F, cnt);
    k2_fused<<<256, 256, 0, stream>>>(c_part, bdec, w1, b1, w2, b2, F, cnt, out);
}

// Round 9
// 94.693 us; speedup vs baseline: 1.2012x; 1.2012x over previous
//
#include <hip/hip_runtime.h>
#include <cstdint>

#define B_    64
#define EMB   1024
#define NO    2048
#define NL    8192
#define LOUT  8190
#define NJ    128
#define NKC   16          // K-chunks in k1
#define KCH   64          // K depth per chunk
#define ALPHA 0.3989422804014327f   // 1/sqrt(2*pi): gelu(x) ~= 0.5x + ALPHA*x^2

// ---------------------------------------------------------------------------
// K1: split-K GEMM. c_part[kc][b][o] = sum_{e in chunk} token[b,e]*wdec[e,o].
// grid = 32 o-tiles(64) x 16 K-chunks(64) = 512 blocks (2/CU). Round-7
// verified version. Fusion of downstream stages is measurably harmful
// (R6: +6us winner-block tail; R8: +19us spin-barrier tail) — keep 3 kernels.
// ---------------------------------------------------------------------------
__global__ __launch_bounds__(256) void k1_gemm(const float* __restrict__ token,
                                               const float* __restrict__ wdec,
                                               float* __restrict__ c_part) {
    const int ot  = blockIdx.x & 31;
    const int kc  = blockIdx.x >> 5;
    const int o0  = ot * 64;
    const int kb  = kc * KCH;
    const int tid = threadIdx.x;
    const int og  = tid & 15;
    const int bg  = tid >> 4;

    __shared__ float tokT[KCH][68];   // [k][b], padded
    __shared__ float wdS[KCH][68];    // [k][o], padded

    {
        const int k4 = tid & 15;      // k-group of 4
        const int b0 = tid >> 4;
#pragma unroll
        for (int i = 0; i < 4; ++i) { // token tile 64b x 64k, coalesced along k
            int b = b0 + i * 16;
            float4 v = *(const float4*)&token[b * EMB + kb + k4 * 4];
            tokT[k4 * 4 + 0][b] = v.x;
            tokT[k4 * 4 + 1][b] = v.y;
            tokT[k4 * 4 + 2][b] = v.z;
            tokT[k4 * 4 + 3][b] = v.w;
        }
        const int o4 = tid & 15;
        const int k0 = tid >> 4;
#pragma unroll
        for (int i = 0; i < 4; ++i) { // wdec tile 64k x 64o, coalesced along o
            int k = k0 + i * 16;
            *(float4*)&wdS[k][o4 * 4] = *(const float4*)&wdec[(kb + k) * NO + o0 + o4 * 4];
        }
    }
    __syncthreads();

    float acc[4][4] = {};
#pragma unroll 4
    for (int k = 0; k < KCH; ++k) {
        float4 tv = *(const float4*)&tokT[k][bg * 4];
        float4 wv = *(const float4*)&wdS[k][og * 4];
        acc[0][0] = fmaf(tv.x, wv.x, acc[0][0]);
        acc[0][1] = fmaf(tv.x, wv.y, acc[0][1]);
        acc[0][2] = fmaf(tv.x, wv.z, acc[0][2]);
        acc[0][3] = fmaf(tv.x, wv.w, acc[0][3]);
        acc[1][0] = fmaf(tv.y, wv.x, acc[1][0]);
        acc[1][1] = fmaf(tv.y, wv.y, acc[1][1]);
        acc[1][2] = fmaf(tv.y, wv.z, acc[1][2]);
        acc[1][3] = fmaf(tv.y, wv.w, acc[1][3]);
        acc[2][0] = fmaf(tv.z, wv.x, acc[2][0]);
        acc[2][1] = fmaf(tv.z, wv.y, acc[2][1]);
        acc[2][2] = fmaf(tv.z, wv.z, acc[2][2]);
        acc[2][3] = fmaf(tv.z, wv.w, acc[2][3]);
        acc[3][0] = fmaf(tv.w, wv.x, acc[3][0]);
        acc[3][1] = fmaf(tv.w, wv.y, acc[3][1]);
        acc[3][2] = fmaf(tv.w, wv.z, acc[3][2]);
        acc[3][3] = fmaf(tv.w, wv.w, acc[3][3]);
    }

    float* cp = c_part + kc * (B_ * NO) + o0 + og * 4;
#pragma unroll
    for (int ib = 0; ib < 4; ++ib) {
        float4 v = {acc[ib][0], acc[ib][1], acc[ib][2], acc[ib][3]};
        *(float4*)&cp[(bg * 4 + ib) * NO] = v;
    }
}

// ---------------------------------------------------------------------------
// K2: fold, round-7-verified. 256 blocks x 256 thr, one block per
// (b, j-quarter), inline split-K reduce, XCD-grouped blockIdx remap (the 4
// quarter-blocks of a b share bid%8 -> same XCD -> c_part slice L2-reused).
// Produces quarter-partial spectrum F_part[b][quarter][64].
// ---------------------------------------------------------------------------
__global__ __launch_bounds__(256) void k2_fused(const float* __restrict__ c_part,
                                                const float* __restrict__ bdec,
                                                const float* __restrict__ w1,
                                                const float* __restrict__ b1,
                                                const float* __restrict__ w2,
                                                const float* __restrict__ b2,
                                                float* __restrict__ F_part) {
    const int bid = blockIdx.x;
    const int xg  = bid & 7;                 // XCD slot
    const int q4  = (bid >> 3) & 3;          // j-quarter
    const int b   = (bid >> 5) * 8 + xg;     // batch
    const int j0  = q4 * 32;
    const int t   = threadIdx.x;

    __shared__ float cwS[2048];          // summed c + bdec, [w*32+m]
    __shared__ float w1S[2048];          // w1 slice, [w*32+jl]
    __shared__ float w2S[32], b1S[32];
    __shared__ float aspec[32 * 32];     // [jl*32 + m]: C_k at 2k, S_k at 2k+1
    __shared__ float FpS[4][64];

    // ---- stage: sum the 16 split-K partials + bdec (inline reduce) ----
    {
        const float4* cp4 = (const float4*)c_part;
        const float4* bd4 = (const float4*)bdec;
#pragma unroll
        for (int i = 0; i < 2; ++i) {
            int s = t + i * 256;                 // float4 slot 0..511
            float4 v = bd4[s];
#pragma unroll
            for (int kc = 0; kc < NKC; ++kc) {
                float4 c = cp4[kc * 32768 + b * 512 + s];
                v.x += c.x; v.y += c.y; v.z += c.z; v.w += c.w;
            }
            ((float4*)cwS)[s] = v;
        }
#pragma unroll
        for (int i = 0; i < 8; ++i) {
            int e = t + i * 256;
            int w = e >> 5, jl = e & 31;
            w1S[e] = w1[w * 128 + j0 + jl];
        }
        if (t < 32) { w2S[t] = w2[j0 + t]; b1S[t] = b1[j0 + t]; }
    }
    __syncthreads();

    // ---- a-spectrum: thread (jl = t>>3, m4 = t&7) owns 4 consecutive m ----
    {
        const int m4 = t & 7, jl = t >> 3;
        float4 acc = {0.f, 0.f, 0.f, 0.f};
        const float4* cw4 = (const float4*)cwS;
        for (int w = 0; w < 64; ++w) {
            float4 cv = cw4[w * 8 + m4];
            float  wv = w1S[w * 32 + jl];
            acc.x = fmaf(cv.x, wv, acc.x);
            acc.y = fmaf(cv.y, wv, acc.y);
            acc.z = fmaf(cv.z, wv, acc.z);
            acc.w = fmaf(cv.w, wv, acc.w);
        }
        const float s2 = 2.0f / NL;
        if (m4 == 0) {
            acc.x = acc.x * (1.0f / NL) + b1S[jl];  // C_0 = A0 (incl b1)
            acc.y = 0.f;                            // S_0 = 0 (DC imag ignored)
            acc.z *= s2; acc.w *= -s2;
        } else {
            acc.x *= s2; acc.y *= -s2; acc.z *= s2; acc.w *= -s2;
        }
        ((float4*)aspec)[jl * 8 + m4] = acc;
    }
    __syncthreads();

    // ---- gather-fold: thread (m = t&31, jq = t>>5) covers 4 j's ----
    {
        const int m  = t & 31;
        const int jq = t >> 5;
        float rc = 0.f, rs = 0.f;
        for (int r = 0; r < 4; ++r) {
            const int jl = r * 8 + jq;
            const float* A = aspec + jl * 32;
            const float C0 = A[0];
            float Qc, Qs, lc, ls;
            if (m == 0) {
                float ssum = 0.f;
#pragma unroll
                for (int k = 1; k <= 15; ++k)
                    ssum += A[2 * k] * A[2 * k] + A[2 * k + 1] * A[2 * k + 1];
                Qc = fmaf(C0, C0, 0.5f * ssum);
                Qs = 0.f; lc = C0; ls = 0.f;
            } else {
                lc = (m <= 15) ? A[2 * m]     : 0.f;
                ls = (m <= 15) ? A[2 * m + 1] : 0.f;
                Qc = 2.f * C0 * lc;
                Qs = 2.f * C0 * ls;
                int lo = m - 15; if (lo < 1)  lo = 1;
                int hi = m - 1;  if (hi > 15) hi = 15;
                for (int k1 = lo; k1 <= hi; ++k1) {        // sum-combinations
                    int k2 = m - k1;
                    float c1 = A[2 * k1], s1 = A[2 * k1 + 1];
                    float c2 = A[2 * k2], sv = A[2 * k2 + 1];
                    Qc = fmaf(0.5f, fmaf(c1, c2, -s1 * sv), Qc);
                    Qs = fmaf(0.5f, fmaf(c1, sv,  s1 * c2), Qs);
                }
                for (int k = 1; k <= 15 - m; ++k) {        // diff-combinations
                    float ch = A[2 * (k + m)], sh = A[2 * (k + m) + 1];
                    float cl = A[2 * k],       sl = A[2 * k + 1];
                    Qc = fmaf(ch, cl, Qc); Qc = fmaf(sh, sl, Qc);
                    Qs = fmaf(sh, cl, Qs); Qs = fmaf(-ch, sl, Qs);
                }
            }
            const float wj = w2S[jl];
            rc += wj * fmaf(ALPHA, Qc, 0.5f * lc);
            rs += wj * fmaf(ALPHA, Qs, 0.5f * ls);
        }
        rc += __shfl_xor(rc, 32);
        rs += __shfl_xor(rs, 32);
        if ((t & 32) == 0) {
            FpS[t >> 6][m]      = rc;
            FpS[t >> 6][32 + m] = rs;
        }
    }
    __syncthreads();
    if (t < 32) {
        float Fc = FpS[0][t] + FpS[1][t] + FpS[2][t] + FpS[3][t];
        float Fs = FpS[0][32 + t] + FpS[1][32 + t] + FpS[2][32 + t] + FpS[3][32 + t];
        if (t == 0 && q4 == 0) Fc += b2[0];
        // F_part layout: [b][quarter][64] so k3's gather is b-local
        F_part[(b * 4 + q4) * 64 + t]      = Fc;
        F_part[(b * 4 + q4) * 64 + 32 + t] = Fs;
    }
}

// ---------------------------------------------------------------------------
// K3: evaluate the 61-term trig series, summing the 4 quarter-partials of F.
// 4-fold symmetry (HW-verified): w0*2048 = pi/2, so point t+2048q uses basis
// (cos k0, sin k0) permuted by (k*q mod 4). One recurrence pass with 6
// bucketed accumulators yields 4 outputs.
//   out(t+2048q) = Fc0 + A0 + [q=0: A1+A2+A3 | q=1: B1-A2-B3 |
//                              q=2: -A1+A2-A3 | q=3: -B1-A2+B3]
//   A_r = sum_{k≡r(4)} (Fc_k ck + Fs_k sk), B_r = sum_{k≡r(4)} (Fs_k ck - Fc_k sk)
// grid = 64 b x 4 chunks; thread does 2 base-points t in [0,2048).
// ---------------------------------------------------------------------------
__global__ __launch_bounds__(256) void k3_eval(const float* __restrict__ F_part,
                                               float* __restrict__ out) {
    const int b     = blockIdx.x >> 2;
    const int chunk = blockIdx.x & 3;
    __shared__ float Fsh[64];
    if (threadIdx.x < 64) {
        const float* Fb = F_part + b * 256 + threadIdx.x;
        Fsh[threadIdx.x] = Fb[0] + Fb[64] + Fb[128] + Fb[192];
    }
    __syncthreads();

    const float w0 = 6.283185307179586f / (float)NL;
#pragma unroll
    for (int i = 0; i < 2; ++i) {
        int t = chunk * 512 + i * 256 + threadIdx.x;   // [0, 2048)
        float s1, c1;
        __sincosf(w0 * (float)t, &s1, &c1);
        float A0 = 0.f, A1 = 0.f, A2 = 0.f, A3 = 0.f, B1 = 0.f, B3 = 0.f;
        float ckm = 1.f, ck = c1, skm = 0.f, sk = s1;
        const float tc = 2.f * c1;
#pragma unroll
        for (int k = 1; k <= 30; ++k) {
            const float fc = Fsh[k], fs = Fsh[32 + k];
            if ((k & 3) == 0) {
                A0 = fmaf(fc, ck, A0); A0 = fmaf(fs, sk, A0);
            } else if ((k & 3) == 1) {
                A1 = fmaf(fc, ck, A1); A1 = fmaf(fs, sk, A1);
                B1 = fmaf(fs, ck, B1); B1 = fmaf(-fc, sk, B1);
            } else if ((k & 3) == 2) {
                A2 = fmaf(fc, ck, A2); A2 = fmaf(fs, sk, A2);
            } else {
                A3 = fmaf(fc, ck, A3); A3 = fmaf(fs, sk, A3);
                B3 = fmaf(fs, ck, B3); B3 = fmaf(-fc, sk, B3);
            }
            float cn = fmaf(tc, ck, -ckm);
            float sn = fmaf(tc, sk, -skm);
            ckm = ck; ck = cn;
            skm = sk; sk = sn;
        }
        const float S = Fsh[0] + A0;
        float* ob = out + b * LOUT;
        ob[t]        = S + A1 + A2 + A3;
        ob[t + 2048] = S + B1 - A2 - B3;
        ob[t + 4096] = S - A1 + A2 - A3;
        if (t < LOUT - 6144)
            ob[t + 6144] = S - B1 - A2 + B3;
    }
}

extern "C" void kernel_launch(void* const* d_in, const int* in_sizes, int n_in,
                              void* d_out, int out_size, void* d_ws, size_t ws_size,
                              hipStream_t stream) {
    const float* token = (const float*)d_in[0];
    // d_in[1] = x_len (8192, hard-coded)
    const float* wdec  = (const float*)d_in[2];
    const float* bdec  = (const float*)d_in[3];
    const float* w1    = (const float*)d_in[4];
    const float* b1    = (const float*)d_in[5];
    const float* w2    = (const float*)d_in[6];
    const float* b2    = (const float*)d_in[7];
    float* out = (float*)d_out;

    float* c_part = (float*)d_ws;                    // 16*64*2048 f32 = 8 MB
    float* F_part = c_part + NKC * B_ * NO;          // 64*4*64 f32 = 64 KB

    k1_gemm<<<512, 256, 0, stream>>>(token, wdec, c_part);
    k2_fused<<<256, 256, 0, stream>>>(c_part, bdec, w1, b1, w2, b2, F_part);
    k3_eval<<<256, 256, 0, stream>>>(F_part, out);
}